// Round 2
// baseline (1801.226 us; speedup 1.0000x reference)
//
#include <hip/hip_runtime.h>

#define NN 100000      // nodes per type (authors == papers == 100000)
#define NE 500000      // edges per relation
#define HD 128         // hidden
#define NBLK 391       // ceil(NN/256)

typedef float f32x4v __attribute__((ext_vector_type(4)));
typedef short s16x8  __attribute__((ext_vector_type(8)));

static __device__ __forceinline__ void add4(float4& c, const float4 b){
  c.x += b.x; c.y += b.y; c.z += b.z; c.w += b.w;
}

// float -> bf16 bits, RNE
static __device__ __forceinline__ unsigned f2bf_bits(float f){
  unsigned u = __float_as_uint(f);
  return (u + 0x7FFF + ((u >> 16) & 1)) >> 16;
}

static __device__ __forceinline__ void split8(const float* a, s16x8& hi, s16x8& lo){
  #pragma unroll
  for (int j = 0; j < 8; ++j){
    float f = a[j];
    unsigned hb = f2bf_bits(f);
    float hf = __uint_as_float(hb << 16);
    float lf = f - hf;
    hi[j] = (short)hb;
    lo[j] = (short)f2bf_bits(lf);
  }
}

// ============================ CSR build =================================
__global__ void k_count(const int* __restrict__ ei_pa, const int* __restrict__ ei_ap,
                        int* __restrict__ deg2){
  int idx = blockIdx.x * 256 + threadIdx.x;
  if (idx < NE)        atomicAdd(&deg2[      ei_pa[NE + idx]], 1);
  else if (idx < 2*NE) atomicAdd(&deg2[NN + ei_ap[NE + (idx - NE)]], 1);
}

__global__ void k_bsum(const int* __restrict__ deg2, int* __restrict__ bsum){
  int rel = blockIdx.x / NBLK, b = blockIdx.x % NBLK;
  int i = b*256 + threadIdx.x;
  int v = (i < NN) ? deg2[rel*NN + i] : 0;
  __shared__ int s[256];
  s[threadIdx.x] = v; __syncthreads();
  for (int o = 128; o > 0; o >>= 1){
    if (threadIdx.x < o) s[threadIdx.x] += s[threadIdx.x + o];
    __syncthreads();
  }
  if (threadIdx.x == 0) bsum[rel*512 + b] = s[0];
}

__global__ void k_bscan(const int* __restrict__ bsum, int* __restrict__ bsoff){
  int rel = blockIdx.x, t = threadIdx.x;
  int v = (t < NBLK) ? bsum[rel*512 + t] : 0;
  __shared__ int s[512];
  s[t] = v; __syncthreads();
  for (int o = 1; o < 512; o <<= 1){
    int x = (t >= o) ? s[t - o] : 0;
    __syncthreads();
    s[t] += x;
    __syncthreads();
  }
  bsoff[rel*512 + t] = s[t] - v;   // exclusive
}

__global__ void k_scanC(const int* __restrict__ deg2, const int* __restrict__ bsoff,
                        int* __restrict__ off2, int* __restrict__ cur2){
  int rel = blockIdx.x / NBLK, b = blockIdx.x % NBLK;
  int i = b*256 + threadIdx.x, t = threadIdx.x;
  int v = (i < NN) ? deg2[rel*NN + i] : 0;
  __shared__ int s[256];
  s[t] = v; __syncthreads();
  for (int o = 1; o < 256; o <<= 1){
    int x = (t >= o) ? s[t - o] : 0;
    __syncthreads();
    s[t] += x;
    __syncthreads();
  }
  if (i < NN){
    int o = bsoff[rel*512 + b] + s[t] - v;
    off2[rel*NN + i] = o;
    cur2[rel*NN + i] = o;
  }
}

__global__ void k_fill(const int* __restrict__ ei_pa, const int* __restrict__ ei_ap,
                       int* __restrict__ cur2,
                       int* __restrict__ col_pa, int* __restrict__ col_ap){
  int idx = blockIdx.x * 256 + threadIdx.x;
  if (idx < NE){
    int s = ei_pa[idx], d = ei_pa[NE + idx];
    int pos = atomicAdd(&cur2[d], 1);
    col_pa[pos] = s;
  } else if (idx < 2*NE){
    int e = idx - NE;
    int s = ei_ap[e], d = ei_ap[NE + e];
    int pos = atomicAdd(&cur2[NN + d], 1);
    col_ap[pos] = s;
  }
}

// ============================ weight folding ============================
// W' = wd @ wu_half (fp32), written TRANSPOSED as bf16 hi/lo: Bt[n][k]
struct FoldDesc { const float* A; const float* B; short* Ch; short* Cl; };
struct FoldArgs { FoldDesc d[8]; int rs[9]; };

__global__ void k_fold(FoldArgs fa){
  int row = blockIdx.x;
  int seg = 0;
  #pragma unroll
  for (int s = 0; s < 8; ++s) if (row >= fa.rs[s+1]) seg = s + 1;
  int m = row - fa.rs[seg];             // row of W' (i.e. k index)
  int Krows = fa.rs[seg+1] - fa.rs[seg];
  const float* A = fa.d[seg].A + (size_t)m * 128;
  const float* B = fa.d[seg].B;
  int n = threadIdx.x;
  float acc = 0.f;
  for (int k = 0; k < 128; ++k) acc += A[k] * B[k*128 + n];
  unsigned hb = f2bf_bits(acc);
  float hf = __uint_as_float(hb << 16);
  unsigned lb = f2bf_bits(acc - hf);
  fa.d[seg].Ch[(size_t)n*Krows + m] = (short)hb;
  fa.d[seg].Cl[(size_t)n*Krows + m] = (short)lb;
}

// b' = bd@wu_top + bs@wu_bot + bu
struct BiasArgs { const float* bd[4]; const float* bs[4]; const float* wu[4];
                  const float* bu[4]; float* outb[4]; };
__global__ void k_biasfold(BiasArgs ba){
  int s = blockIdx.x, j = threadIdx.x;
  const float* wu = ba.wu[s];
  float acc = ba.bu[s][j];
  for (int k = 0; k < 128; ++k)
    acc += ba.bd[s][k] * wu[k*128 + j] + ba.bs[s][k] * wu[(128 + k)*128 + j];
  ba.outb[s][j] = acc;
}

// ============================ MFMA GEMM =================================
// C[M,128] = A[M,K] @ B[K,128] (+bias) (+extra), A fp32, B pre-split bf16
// hi/lo stored transposed [n][k]. Split-bf16 3-product => fp32-level accuracy.
// No LDS, no barriers: fragments loaded straight from global.
// Wave w handles rows [blk*128 + w*32, +32) x all 128 cols.
__global__ __launch_bounds__(256)
void k_gemm_mfma(const float* __restrict__ A, const short* __restrict__ Bh,
                 const short* __restrict__ Bl, const float* __restrict__ bias,
                 const float* __restrict__ extra, float* __restrict__ C,
                 int M, int K)
{
  const int tid  = threadIdx.x;
  const int wave = tid >> 6, lane = tid & 63;
  const int li   = lane & 15, quad = lane >> 4;
  const int rowT = blockIdx.x * 128 + wave * 32;

  f32x4v acc[2][8];
  #pragma unroll
  for (int mt = 0; mt < 2; ++mt)
    #pragma unroll
    for (int nt = 0; nt < 8; ++nt)
      acc[mt][nt] = (f32x4v){0.f, 0.f, 0.f, 0.f};

  for (int k0 = 0; k0 < K; k0 += 32){
    s16x8 ah[2], al[2];
    #pragma unroll
    for (int mt = 0; mt < 2; ++mt){
      int row = rowT + mt*16 + li;
      float av[8];
      if (row < M){
        const float* ap = A + (size_t)row*K + k0 + quad*8;
        float4 p0 = *(const float4*)ap;
        float4 p1 = *(const float4*)(ap + 4);
        av[0]=p0.x; av[1]=p0.y; av[2]=p0.z; av[3]=p0.w;
        av[4]=p1.x; av[5]=p1.y; av[6]=p1.z; av[7]=p1.w;
      } else {
        #pragma unroll
        for (int j = 0; j < 8; ++j) av[j] = 0.f;
      }
      split8(av, ah[mt], al[mt]);
    }
    #pragma unroll
    for (int nt = 0; nt < 8; ++nt){
      size_t boff = (size_t)(nt*16 + li)*K + k0 + quad*8;
      s16x8 bh = *(const s16x8*)(Bh + boff);
      s16x8 bl = *(const s16x8*)(Bl + boff);
      #pragma unroll
      for (int mt = 0; mt < 2; ++mt){
        acc[mt][nt] = __builtin_amdgcn_mfma_f32_16x16x32_bf16(ah[mt], bh, acc[mt][nt], 0, 0, 0);
        acc[mt][nt] = __builtin_amdgcn_mfma_f32_16x16x32_bf16(al[mt], bh, acc[mt][nt], 0, 0, 0);
        acc[mt][nt] = __builtin_amdgcn_mfma_f32_16x16x32_bf16(ah[mt], bl, acc[mt][nt], 0, 0, 0);
      }
    }
  }

  // epilogue: C/D layout col=lane&15, row=quad*4+reg  [m89-verified]
  #pragma unroll
  for (int mt = 0; mt < 2; ++mt){
    #pragma unroll
    for (int r = 0; r < 4; ++r){
      int grow = rowT + mt*16 + quad*4 + r;
      if (grow >= M) continue;
      const float* erow = extra ? extra + (size_t)grow*128 : nullptr;
      float* crow = C + (size_t)grow*128;
      #pragma unroll
      for (int nt = 0; nt < 8; ++nt){
        int gcol = nt*16 + li;
        float v = acc[mt][nt][r];
        if (bias) v += bias[gcol];
        if (erow) v += erow[gcol];
        crow[gcol] = v;
      }
    }
  }
}

// ============================ mean-aggregate ============================
__global__ void k_agg(const float* __restrict__ t, const int* __restrict__ off,
                      const int* __restrict__ deg, const int* __restrict__ col,
                      float* __restrict__ o){
  int d = blockIdx.x * 2 + (threadIdx.x >> 7);
  int c = threadIdx.x & 127;
  int s0 = off[d], cnt = deg[d];
  float acc = 0.f;
  for (int i = 0; i < cnt; ++i){
    int s = col[s0 + i];
    acc += t[(size_t)s*128 + c];
  }
  float inv = 1.0f / (float)(cnt > 0 ? cnt : 1);
  o[(size_t)d*128 + c] = acc * inv;
}

// ============================ batchnorm + lrelu =========================
__global__ void k_stats(const float* __restrict__ x, float* __restrict__ stats, int M){
  int c = threadIdx.x & 127, half = threadIdx.x >> 7;
  float s = 0.f, s2 = 0.f;
  for (int r = blockIdx.x*2 + half; r < M; r += gridDim.x*2){
    float v = x[(size_t)r*128 + c];
    s += v; s2 += v*v;
  }
  __shared__ float sh[256];
  sh[threadIdx.x] = s; __syncthreads();
  if (half == 0) atomicAdd(&stats[c], s + sh[threadIdx.x + 128]);
  __syncthreads();
  sh[threadIdx.x] = s2; __syncthreads();
  if (half == 0) atomicAdd(&stats[128 + c], s2 + sh[threadIdx.x + 128]);
}

__global__ void k_bnprep(const float* __restrict__ stats, const float* __restrict__ g,
                         const float* __restrict__ b, float* __restrict__ sc, int M){
  int c = threadIdx.x;
  float invN = 1.0f / (float)M;
  float m  = stats[c] * invN;
  float var = stats[128 + c] * invN - m*m;
  float scale = g[c] / sqrtf(var + 1.0f);
  sc[c] = scale;
  sc[128 + c] = b[c] - m*scale;
}

__global__ void k_bn(float* __restrict__ x, const float* __restrict__ sc, int M){
  int idx = blockIdx.x*256 + threadIdx.x;   // float4 index
  if (idx >= M*32) return;
  int c = (idx & 31) * 4;
  float4 v = ((float4*)x)[idx];
  float s0=sc[c],s1=sc[c+1],s2=sc[c+2],s3=sc[c+3];
  float h0=sc[128+c],h1=sc[129+c],h2=sc[130+c],h3=sc[131+c];
  v.x = v.x*s0 + h0; v.x = v.x >= 0.f ? v.x : 0.01f*v.x;
  v.y = v.y*s1 + h1; v.y = v.y >= 0.f ? v.y : 0.01f*v.y;
  v.z = v.z*s2 + h2; v.z = v.z >= 0.f ? v.z : 0.01f*v.z;
  v.w = v.w*s3 + h3; v.w = v.w >= 0.f ? v.w : 0.01f*v.w;
  ((float4*)x)[idx] = v;
}

// ============================ heads =====================================
template<int LC>
__global__ void k_head(const float* __restrict__ h, const float* __restrict__ w,
                       const float* __restrict__ b, float* __restrict__ o, int M){
  __shared__ float ws[128*LC];
  __shared__ float bs[LC];
  for (int i = threadIdx.x; i < 128*LC; i += 256) ws[i] = w[i];
  if (threadIdx.x < LC) bs[threadIdx.x] = b[threadIdx.x];
  __syncthreads();
  int r = blockIdx.x*256 + threadIdx.x;
  if (r >= M) return;
  float acc[LC];
  #pragma unroll
  for (int c = 0; c < LC; ++c) acc[c] = bs[c];
  const float4* hr = (const float4*)(h + (size_t)r*128);
  for (int k4 = 0; k4 < 32; ++k4){
    float4 v = hr[k4];
    int k = k4*4;
    #pragma unroll
    for (int c = 0; c < LC; ++c)
      acc[c] += v.x*ws[k*LC+c] + v.y*ws[(k+1)*LC+c] + v.z*ws[(k+2)*LC+c] + v.w*ws[(k+3)*LC+c];
  }
  #pragma unroll
  for (int c = 0; c < LC; ++c) o[(size_t)r*LC + c] = acc[c];
}

// ============================ launch ====================================
extern "C" void kernel_launch(void* const* d_in, const int* in_sizes, int n_in,
                              void* d_out, int out_size, void* d_ws, size_t ws_size,
                              hipStream_t stream) {
  const float* x_author = (const float*)d_in[0];   // [NN,256]
  const float* x_paper  = (const float*)d_in[1];   // [NN,128]
  const int*   ei_pa    = (const int*)d_in[2];     // [2,NE]
  const int*   ei_ap    = (const int*)d_in[3];     // [2,NE]

  char* p = (char*)d_ws;
  auto alloc = [&](size_t bytes) -> void* {
    void* r = (void*)p; p += (bytes + 255) & ~(size_t)255; return r;
  };
  // folded weights as transposed bf16 hi/lo; segment rows:
  // seg0 w1a_d(256) seg1 w1a_s(128) seg2 w1p_d(128) seg3 w1p_s(256)
  // seg4 w2a_d(128) seg5 w2a_s(128) seg6 w2p_d(128) seg7 w2p_s(128)
  int rows[8] = {256,128,128,256,128,128,128,128};
  short* Wh[8]; short* Wl[8];
  for (int i = 0; i < 8; ++i){
    Wh[i] = (short*)alloc((size_t)rows[i]*128*2);
    Wl[i] = (short*)alloc((size_t)rows[i]*128*2);
  }
  float* w1a_b = (float*)alloc(128*4);      float* w1p_b = (float*)alloc(128*4);
  float* w2a_b = (float*)alloc(128*4);      float* w2p_b = (float*)alloc(128*4);
  float* stats = (float*)alloc(256*4);      float* bnsc  = (float*)alloc(256*4);
  int* deg2  = (int*)alloc(2*NN*4);
  int* off2  = (int*)alloc(2*NN*4);
  int* cur2  = (int*)alloc(2*NN*4);
  int* col_pa = (int*)alloc(NE*4);
  int* col_ap = (int*)alloc(NE*4);
  int* bsum  = (int*)alloc(1024*4);
  int* bsoff = (int*)alloc(1024*4);
  const size_t NB = (size_t)NN * 128;
  float* B1 = (float*)alloc(NB*4);  // h_author (layer1, activated)
  float* B2 = (float*)alloc(NB*4);  // h_paper
  float* B3 = (float*)alloc(NB*4);  // temp src-transform / h_a2
  float* B4 = (float*)alloc(NB*4);  // agg / temp / h_p2

  // ---- CSR build (shared by both layers) ----
  hipMemsetAsync(deg2, 0, 2*NN*4, stream);
  k_count<<<(2*NE + 255)/256, 256, 0, stream>>>(ei_pa, ei_ap, deg2);
  k_bsum <<<2*NBLK, 256, 0, stream>>>(deg2, bsum);
  k_bscan<<<2, 512, 0, stream>>>(bsum, bsoff);
  k_scanC<<<2*NBLK, 256, 0, stream>>>(deg2, bsoff, off2, cur2);
  k_fill <<<(2*NE + 255)/256, 256, 0, stream>>>(ei_pa, ei_ap, cur2, col_pa, col_ap);

  // ---- fold weights ----
  FoldArgs fa;
  const float* wu1a = (const float*)d_in[8];
  const float* wu1p = (const float*)d_in[14];
  const float* wu2a = (const float*)d_in[20];
  const float* wu2p = (const float*)d_in[26];
  fa.d[0] = { (const float*)d_in[6],  wu1a,           Wh[0], Wl[0] };  // wd(256)@wu_top
  fa.d[1] = { (const float*)d_in[4],  wu1a + 128*128, Wh[1], Wl[1] };  // ws(128)@wu_bot
  fa.d[2] = { (const float*)d_in[12], wu1p,           Wh[2], Wl[2] };
  fa.d[3] = { (const float*)d_in[10], wu1p + 128*128, Wh[3], Wl[3] };
  fa.d[4] = { (const float*)d_in[18], wu2a,           Wh[4], Wl[4] };
  fa.d[5] = { (const float*)d_in[16], wu2a + 128*128, Wh[5], Wl[5] };
  fa.d[6] = { (const float*)d_in[24], wu2p,           Wh[6], Wl[6] };
  fa.d[7] = { (const float*)d_in[22], wu2p + 128*128, Wh[7], Wl[7] };
  fa.rs[0] = 0;
  for (int i = 0; i < 8; ++i) fa.rs[i+1] = fa.rs[i] + rows[i];
  k_fold<<<fa.rs[8], 128, 0, stream>>>(fa);

  BiasArgs ba;
  ba.bd[0]=(const float*)d_in[7];  ba.bs[0]=(const float*)d_in[5];  ba.wu[0]=wu1a; ba.bu[0]=(const float*)d_in[9];  ba.outb[0]=w1a_b;
  ba.bd[1]=(const float*)d_in[13]; ba.bs[1]=(const float*)d_in[11]; ba.wu[1]=wu1p; ba.bu[1]=(const float*)d_in[15]; ba.outb[1]=w1p_b;
  ba.bd[2]=(const float*)d_in[19]; ba.bs[2]=(const float*)d_in[17]; ba.wu[2]=wu2a; ba.bu[2]=(const float*)d_in[21]; ba.outb[2]=w2a_b;
  ba.bd[3]=(const float*)d_in[25]; ba.bs[3]=(const float*)d_in[23]; ba.wu[3]=wu2p; ba.bu[3]=(const float*)d_in[27]; ba.outb[3]=w2p_b;
  k_biasfold<<<4, 128, 0, stream>>>(ba);

  const int GEMM_GRID = (NN + 127)/128;   // 782
  const int* off_pa = off2;        const int* deg_pa = deg2;
  const int* off_ap = off2 + NN;   const int* deg_ap = deg2 + NN;

  auto bn_block = [&](float* h, const float* g, const float* be){
    hipMemsetAsync(stats, 0, 256*4, stream);
    k_stats <<<256, 256, 0, stream>>>(h, stats, NN);
    k_bnprep<<<1, 128, 0, stream>>>(stats, g, be, bnsc, NN);
    k_bn    <<<NN*32/256, 256, 0, stream>>>(h, bnsc, NN);
  };

  // ---- layer 1, author (p2a) ----
  k_gemm_mfma<<<GEMM_GRID, 256, 0, stream>>>(x_paper,  Wh[1], Wl[1], nullptr, nullptr, B3, NN, 128);
  k_agg <<<NN/2, 256, 0, stream>>>(B3, off_pa, deg_pa, col_pa, B4);
  k_gemm_mfma<<<GEMM_GRID, 256, 0, stream>>>(x_author, Wh[0], Wl[0], w1a_b, B4, B1, NN, 256);
  bn_block(B1, (const float*)d_in[28], (const float*)d_in[29]);

  // ---- layer 1, paper (a2p) ----
  k_gemm_mfma<<<GEMM_GRID, 256, 0, stream>>>(x_author, Wh[3], Wl[3], nullptr, nullptr, B3, NN, 256);
  k_agg <<<NN/2, 256, 0, stream>>>(B3, off_ap, deg_ap, col_ap, B4);
  k_gemm_mfma<<<GEMM_GRID, 256, 0, stream>>>(x_paper,  Wh[2], Wl[2], w1p_b, B4, B2, NN, 128);
  bn_block(B2, (const float*)d_in[30], (const float*)d_in[31]);

  // ---- layer 2, author (p2a; src = B2, dst = B1) ----
  k_gemm_mfma<<<GEMM_GRID, 256, 0, stream>>>(B2, Wh[5], Wl[5], nullptr, nullptr, B3, NN, 128);
  k_agg <<<NN/2, 256, 0, stream>>>(B3, off_pa, deg_pa, col_pa, B4);
  k_gemm_mfma<<<GEMM_GRID, 256, 0, stream>>>(B1, Wh[4], Wl[4], w2a_b, B4, B3, NN, 128);  // h_a2 -> B3
  bn_block(B3, (const float*)d_in[32], (const float*)d_in[33]);
  k_head<4><<<(NN + 255)/256, 256, 0, stream>>>(B3, (const float*)d_in[36], (const float*)d_in[37],
                                                (float*)d_out, NN);

  // ---- layer 2, paper (a2p; src = B1, dst = B2) ----
  k_gemm_mfma<<<GEMM_GRID, 256, 0, stream>>>(B1, Wh[7], Wl[7], nullptr, nullptr, B4, NN, 128);
  k_agg <<<NN/2, 256, 0, stream>>>(B4, off_ap, deg_ap, col_ap, B1);          // agg -> B1 (free)
  k_gemm_mfma<<<GEMM_GRID, 256, 0, stream>>>(B2, Wh[6], Wl[6], w2p_b, B1, B4, NN, 128);  // h_p2 -> B4
  bn_block(B4, (const float*)d_in[34], (const float*)d_in[35]);
  k_head<7><<<(NN + 255)/256, 256, 0, stream>>>(B4, (const float*)d_in[38], (const float*)d_in[39],
                                                (float*)d_out + (size_t)NN*4, NN);
}

// Round 3
// 1743.942 us; speedup vs baseline: 1.0328x; 1.0328x over previous
//
#include <hip/hip_runtime.h>

#define NN 100000      // nodes per type (authors == papers == 100000)
#define NE 500000      // edges per relation
#define HD 128         // hidden
#define NBLK 391       // ceil(NN/256)

typedef float f32x4v __attribute__((ext_vector_type(4)));
typedef short s16x8  __attribute__((ext_vector_type(8)));

// float -> bf16 bits, RNE
static __device__ __forceinline__ unsigned f2bf_bits(float f){
  unsigned u = __float_as_uint(f);
  return (u + 0x7FFF + ((u >> 16) & 1)) >> 16;
}

static __device__ __forceinline__ void split8(const float* a, s16x8& hi, s16x8& lo){
  #pragma unroll
  for (int j = 0; j < 8; ++j){
    float f = a[j];
    unsigned hb = f2bf_bits(f);
    float hf = __uint_as_float(hb << 16);
    float lf = f - hf;
    hi[j] = (short)hb;
    lo[j] = (short)f2bf_bits(lf);
  }
}

// ============================ CSR build =================================
__global__ void k_count(const int* __restrict__ ei_pa, const int* __restrict__ ei_ap,
                        int* __restrict__ deg2){
  int idx = blockIdx.x * 256 + threadIdx.x;
  if (idx < NE)        atomicAdd(&deg2[      ei_pa[NE + idx]], 1);
  else if (idx < 2*NE) atomicAdd(&deg2[NN + ei_ap[NE + (idx - NE)]], 1);
}

__global__ void k_bsum(const int* __restrict__ deg2, int* __restrict__ bsum){
  int rel = blockIdx.x / NBLK, b = blockIdx.x % NBLK;
  int i = b*256 + threadIdx.x;
  int v = (i < NN) ? deg2[rel*NN + i] : 0;
  __shared__ int s[256];
  s[threadIdx.x] = v; __syncthreads();
  for (int o = 128; o > 0; o >>= 1){
    if (threadIdx.x < o) s[threadIdx.x] += s[threadIdx.x + o];
    __syncthreads();
  }
  if (threadIdx.x == 0) bsum[rel*512 + b] = s[0];
}

__global__ void k_bscan(const int* __restrict__ bsum, int* __restrict__ bsoff){
  int rel = blockIdx.x, t = threadIdx.x;
  int v = (t < NBLK) ? bsum[rel*512 + t] : 0;
  __shared__ int s[512];
  s[t] = v; __syncthreads();
  for (int o = 1; o < 512; o <<= 1){
    int x = (t >= o) ? s[t - o] : 0;
    __syncthreads();
    s[t] += x;
    __syncthreads();
  }
  bsoff[rel*512 + t] = s[t] - v;   // exclusive
}

__global__ void k_scanC(const int* __restrict__ deg2, const int* __restrict__ bsoff,
                        int* __restrict__ off2, int* __restrict__ cur2){
  int rel = blockIdx.x / NBLK, b = blockIdx.x % NBLK;
  int i = b*256 + threadIdx.x, t = threadIdx.x;
  int v = (i < NN) ? deg2[rel*NN + i] : 0;
  __shared__ int s[256];
  s[t] = v; __syncthreads();
  for (int o = 1; o < 256; o <<= 1){
    int x = (t >= o) ? s[t - o] : 0;
    __syncthreads();
    s[t] += x;
    __syncthreads();
  }
  if (i < NN){
    int o = bsoff[rel*512 + b] + s[t] - v;
    off2[rel*NN + i] = o;
    cur2[rel*NN + i] = o;
  }
}

__global__ void k_fill(const int* __restrict__ ei_pa, const int* __restrict__ ei_ap,
                       int* __restrict__ cur2,
                       int* __restrict__ col_pa, int* __restrict__ col_ap){
  int idx = blockIdx.x * 256 + threadIdx.x;
  if (idx < NE){
    int s = ei_pa[idx], d = ei_pa[NE + idx];
    int pos = atomicAdd(&cur2[d], 1);
    col_pa[pos] = s;
  } else if (idx < 2*NE){
    int e = idx - NE;
    int s = ei_ap[e], d = ei_ap[NE + e];
    int pos = atomicAdd(&cur2[NN + d], 1);
    col_ap[pos] = s;
  }
}

// ============================ weight folding ============================
// W'[k][n] = (wd @ wu_half)[k][n], written in MFMA B-FRAGMENT ORDER, bf16
// hi/lo: frag (nt, kc, h) occupies 512 shorts; within it, lane*8 + j where
// lane = quad*16 + (n&15), k = kc*32 + quad*8 + j. GEMM B-load becomes
// base + lane*16 bytes: perfectly coalesced, L2-resident.
struct FoldDesc { const float* A; const float* B; short* Cf; };
struct FoldArgs { FoldDesc d[8]; int rs[9]; };

__global__ void k_fold(FoldArgs fa){
  int row = blockIdx.x;
  int seg = 0;
  #pragma unroll
  for (int s = 0; s < 8; ++s) if (row >= fa.rs[s+1]) seg = s + 1;
  int m = row - fa.rs[seg];             // k index of W'
  int KC = (fa.rs[seg+1] - fa.rs[seg]) >> 5;
  const float* A = fa.d[seg].A + (size_t)m * 128;
  const float* B = fa.d[seg].B;
  int n = threadIdx.x;
  float acc = 0.f;
  for (int k = 0; k < 128; ++k) acc += A[k] * B[k*128 + n];
  unsigned hb = f2bf_bits(acc);
  float hf = __uint_as_float(hb << 16);
  unsigned lb = f2bf_bits(acc - hf);
  int kc = m >> 5, quad = (m >> 3) & 3, j = m & 7;
  int lane = quad*16 + (n & 15), nt = n >> 4;
  size_t fb = (size_t)(nt*KC + kc) * 1024 + lane*8 + j;   // *2 halves *512
  fa.d[seg].Cf[fb]       = (short)hb;
  fa.d[seg].Cf[fb + 512] = (short)lb;
}

// b' = bd@wu_top + bs@wu_bot + bu
struct BiasArgs { const float* bd[4]; const float* bs[4]; const float* wu[4];
                  const float* bu[4]; float* outb[4]; };
__global__ void k_biasfold(BiasArgs ba){
  int s = blockIdx.x, j = threadIdx.x;
  const float* wu = ba.wu[s];
  float acc = ba.bu[s][j];
  for (int k = 0; k < 128; ++k)
    acc += ba.bd[s][k] * wu[k*128 + j] + ba.bs[s][k] * wu[(128 + k)*128 + j];
  ba.outb[s][j] = acc;
}

// ============================ MFMA GEMM =================================
// C[M,128] = A[:, kc0*32 : kc0*32+128] @ W'[128 rows] (+bias)(+extra)(+extra2)
// A fp32 (row stride lda), B pre-split bf16 hi/lo in fragment order.
// Each dispatch covers exactly 4 k-chunks (128 K-elements); K=256 GEMMs run
// as two dispatches (pass2 accumulates pass1's C via extra).
// No LDS, no barriers; fully unrolled K; all loads coalesced.
__global__ __launch_bounds__(256)
void k_gemm_mfma(const float* __restrict__ A, int lda,
                 const short* __restrict__ Bf, int KCtot, int kc0,
                 const float* __restrict__ bias, const float* __restrict__ extra,
                 const float* __restrict__ extra2, float* __restrict__ C, int M)
{
  const int tid  = threadIdx.x;
  const int wave = tid >> 6, lane = tid & 63;
  const int li   = lane & 15, quad = lane >> 4;
  const int rowT = blockIdx.x * 128 + wave * 32;

  f32x4v acc[2][8];
  #pragma unroll
  for (int mt = 0; mt < 2; ++mt)
    #pragma unroll
    for (int nt = 0; nt < 8; ++nt)
      acc[mt][nt] = (f32x4v){0.f, 0.f, 0.f, 0.f};

  #pragma unroll
  for (int kc = 0; kc < 4; ++kc){
    // ---- B frags: coalesced lane*16B loads from fragment-ordered table ----
    s16x8 bh[8], bl[8];
    #pragma unroll
    for (int nt = 0; nt < 8; ++nt){
      const short* fp = Bf + (size_t)(nt*KCtot + kc0 + kc)*1024 + lane*8;
      bh[nt] = *(const s16x8*)fp;
      bl[nt] = *(const s16x8*)(fp + 512);
    }
    // ---- A frags ----
    s16x8 ah[2], al[2];
    #pragma unroll
    for (int mt = 0; mt < 2; ++mt){
      int row = rowT + mt*16 + li;
      float av[8];
      if (row < M){
        const float* ap = A + (size_t)row*lda + (kc0 + kc)*32 + quad*8;
        float4 p0 = *(const float4*)ap;
        float4 p1 = *(const float4*)(ap + 4);
        av[0]=p0.x; av[1]=p0.y; av[2]=p0.z; av[3]=p0.w;
        av[4]=p1.x; av[5]=p1.y; av[6]=p1.z; av[7]=p1.w;
      } else {
        #pragma unroll
        for (int j = 0; j < 8; ++j) av[j] = 0.f;
      }
      split8(av, ah[mt], al[mt]);
    }
    #pragma unroll
    for (int nt = 0; nt < 8; ++nt){
      #pragma unroll
      for (int mt = 0; mt < 2; ++mt){
        acc[mt][nt] = __builtin_amdgcn_mfma_f32_16x16x32_bf16(ah[mt], bh[nt], acc[mt][nt], 0, 0, 0);
        acc[mt][nt] = __builtin_amdgcn_mfma_f32_16x16x32_bf16(al[mt], bh[nt], acc[mt][nt], 0, 0, 0);
        acc[mt][nt] = __builtin_amdgcn_mfma_f32_16x16x32_bf16(ah[mt], bl[nt], acc[mt][nt], 0, 0, 0);
      }
    }
  }

  // epilogue: C/D layout col=lane&15, row=quad*4+reg  [m89-verified]
  #pragma unroll
  for (int mt = 0; mt < 2; ++mt){
    #pragma unroll
    for (int r = 0; r < 4; ++r){
      int grow = rowT + mt*16 + quad*4 + r;
      if (grow >= M) continue;
      const float* erow  = extra  ? extra  + (size_t)grow*128 : nullptr;
      const float* erow2 = extra2 ? extra2 + (size_t)grow*128 : nullptr;
      float* crow = C + (size_t)grow*128;
      #pragma unroll
      for (int nt = 0; nt < 8; ++nt){
        int gcol = nt*16 + li;
        float v = acc[mt][nt][r];
        if (bias)  v += bias[gcol];
        if (erow)  v += erow[gcol];
        if (erow2) v += erow2[gcol];
        crow[gcol] = v;
      }
    }
  }
}

// ============================ mean-aggregate ============================
__global__ void k_agg(const float* __restrict__ t, const int* __restrict__ off,
                      const int* __restrict__ deg, const int* __restrict__ col,
                      float* __restrict__ o){
  int d = blockIdx.x * 2 + (threadIdx.x >> 7);
  int c = threadIdx.x & 127;
  int s0 = off[d], cnt = deg[d];
  float acc = 0.f;
  for (int i = 0; i < cnt; ++i){
    int s = col[s0 + i];
    acc += t[(size_t)s*128 + c];
  }
  float inv = 1.0f / (float)(cnt > 0 ? cnt : 1);
  o[(size_t)d*128 + c] = acc * inv;
}

// ============================ batchnorm + lrelu =========================
__global__ void k_stats(const float* __restrict__ x, float* __restrict__ stats, int M){
  int c = threadIdx.x & 127, half = threadIdx.x >> 7;
  float s = 0.f, s2 = 0.f;
  for (int r = blockIdx.x*2 + half; r < M; r += gridDim.x*2){
    float v = x[(size_t)r*128 + c];
    s += v; s2 += v*v;
  }
  __shared__ float sh[256];
  sh[threadIdx.x] = s; __syncthreads();
  if (half == 0) atomicAdd(&stats[c], s + sh[threadIdx.x + 128]);
  __syncthreads();
  sh[threadIdx.x] = s2; __syncthreads();
  if (half == 0) atomicAdd(&stats[128 + c], s2 + sh[threadIdx.x + 128]);
}

__global__ void k_bnprep(const float* __restrict__ stats, const float* __restrict__ g,
                         const float* __restrict__ b, float* __restrict__ sc, int M){
  int c = threadIdx.x;
  float invN = 1.0f / (float)M;
  float m  = stats[c] * invN;
  float var = stats[128 + c] * invN - m*m;
  float scale = g[c] / sqrtf(var + 1.0f);
  sc[c] = scale;
  sc[128 + c] = b[c] - m*scale;
}

__global__ void k_bn(float* __restrict__ x, const float* __restrict__ sc, int M){
  int idx = blockIdx.x*256 + threadIdx.x;   // float4 index
  if (idx >= M*32) return;
  int c = (idx & 31) * 4;
  float4 v = ((float4*)x)[idx];
  float s0=sc[c],s1=sc[c+1],s2=sc[c+2],s3=sc[c+3];
  float h0=sc[128+c],h1=sc[129+c],h2=sc[130+c],h3=sc[131+c];
  v.x = v.x*s0 + h0; v.x = v.x >= 0.f ? v.x : 0.01f*v.x;
  v.y = v.y*s1 + h1; v.y = v.y >= 0.f ? v.y : 0.01f*v.y;
  v.z = v.z*s2 + h2; v.z = v.z >= 0.f ? v.z : 0.01f*v.z;
  v.w = v.w*s3 + h3; v.w = v.w >= 0.f ? v.w : 0.01f*v.w;
  ((float4*)x)[idx] = v;
}

// ============================ heads =====================================
template<int LC>
__global__ void k_head(const float* __restrict__ h, const float* __restrict__ w,
                       const float* __restrict__ b, float* __restrict__ o, int M){
  __shared__ float ws[128*LC];
  __shared__ float bs[LC];
  for (int i = threadIdx.x; i < 128*LC; i += 256) ws[i] = w[i];
  if (threadIdx.x < LC) bs[threadIdx.x] = b[threadIdx.x];
  __syncthreads();
  int r = blockIdx.x*256 + threadIdx.x;
  if (r >= M) return;
  float acc[LC];
  #pragma unroll
  for (int c = 0; c < LC; ++c) acc[c] = bs[c];
  const float4* hr = (const float4*)(h + (size_t)r*128);
  for (int k4 = 0; k4 < 32; ++k4){
    float4 v = hr[k4];
    int k = k4*4;
    #pragma unroll
    for (int c = 0; c < LC; ++c)
      acc[c] += v.x*ws[k*LC+c] + v.y*ws[(k+1)*LC+c] + v.z*ws[(k+2)*LC+c] + v.w*ws[(k+3)*LC+c];
  }
  #pragma unroll
  for (int c = 0; c < LC; ++c) o[(size_t)r*LC + c] = acc[c];
}

// ============================ launch ====================================
extern "C" void kernel_launch(void* const* d_in, const int* in_sizes, int n_in,
                              void* d_out, int out_size, void* d_ws, size_t ws_size,
                              hipStream_t stream) {
  const float* x_author = (const float*)d_in[0];   // [NN,256]
  const float* x_paper  = (const float*)d_in[1];   // [NN,128]
  const int*   ei_pa    = (const int*)d_in[2];     // [2,NE]
  const int*   ei_ap    = (const int*)d_in[3];     // [2,NE]

  char* p = (char*)d_ws;
  auto alloc = [&](size_t bytes) -> void* {
    void* r = (void*)p; p += (bytes + 255) & ~(size_t)255; return r;
  };
  // folded weights in fragment order (hi/lo interleaved per frag pair):
  // seg0 w1a_d(K=256) seg1 w1a_s(128) seg2 w1p_d(128) seg3 w1p_s(256)
  // seg4 w2a_d(128) seg5 w2a_s(128) seg6 w2p_d(128) seg7 w2p_s(128)
  int rows[8] = {256,128,128,256,128,128,128,128};
  short* Wf[8];
  for (int i = 0; i < 8; ++i) Wf[i] = (short*)alloc((size_t)rows[i]*128*2*2);
  float* w1a_b = (float*)alloc(128*4);      float* w1p_b = (float*)alloc(128*4);
  float* w2a_b = (float*)alloc(128*4);      float* w2p_b = (float*)alloc(128*4);
  float* stats = (float*)alloc(256*4);      float* bnsc  = (float*)alloc(256*4);
  int* deg2  = (int*)alloc(2*NN*4);
  int* off2  = (int*)alloc(2*NN*4);
  int* cur2  = (int*)alloc(2*NN*4);
  int* col_pa = (int*)alloc(NE*4);
  int* col_ap = (int*)alloc(NE*4);
  int* bsum  = (int*)alloc(1024*4);
  int* bsoff = (int*)alloc(1024*4);
  const size_t NB = (size_t)NN * 128;
  float* B1 = (float*)alloc(NB*4);  // h_author (layer1, activated)
  float* B2 = (float*)alloc(NB*4);  // h_paper
  float* B3 = (float*)alloc(NB*4);  // temp src-transform / h_a2
  float* B4 = (float*)alloc(NB*4);  // agg / temp / h_p2

  // ---- CSR build (shared by both layers) ----
  hipMemsetAsync(deg2, 0, 2*NN*4, stream);
  k_count<<<(2*NE + 255)/256, 256, 0, stream>>>(ei_pa, ei_ap, deg2);
  k_bsum <<<2*NBLK, 256, 0, stream>>>(deg2, bsum);
  k_bscan<<<2, 512, 0, stream>>>(bsum, bsoff);
  k_scanC<<<2*NBLK, 256, 0, stream>>>(deg2, bsoff, off2, cur2);
  k_fill <<<(2*NE + 255)/256, 256, 0, stream>>>(ei_pa, ei_ap, cur2, col_pa, col_ap);

  // ---- fold weights ----
  FoldArgs fa;
  const float* wu1a = (const float*)d_in[8];
  const float* wu1p = (const float*)d_in[14];
  const float* wu2a = (const float*)d_in[20];
  const float* wu2p = (const float*)d_in[26];
  fa.d[0] = { (const float*)d_in[6],  wu1a,           Wf[0] };  // wd(256)@wu_top
  fa.d[1] = { (const float*)d_in[4],  wu1a + 128*128, Wf[1] };  // ws(128)@wu_bot
  fa.d[2] = { (const float*)d_in[12], wu1p,           Wf[2] };
  fa.d[3] = { (const float*)d_in[10], wu1p + 128*128, Wf[3] };
  fa.d[4] = { (const float*)d_in[18], wu2a,           Wf[4] };
  fa.d[5] = { (const float*)d_in[16], wu2a + 128*128, Wf[5] };
  fa.d[6] = { (const float*)d_in[24], wu2p,           Wf[6] };
  fa.d[7] = { (const float*)d_in[22], wu2p + 128*128, Wf[7] };
  fa.rs[0] = 0;
  for (int i = 0; i < 8; ++i) fa.rs[i+1] = fa.rs[i] + rows[i];
  k_fold<<<fa.rs[8], 128, 0, stream>>>(fa);

  BiasArgs ba;
  ba.bd[0]=(const float*)d_in[7];  ba.bs[0]=(const float*)d_in[5];  ba.wu[0]=wu1a; ba.bu[0]=(const float*)d_in[9];  ba.outb[0]=w1a_b;
  ba.bd[1]=(const float*)d_in[13]; ba.bs[1]=(const float*)d_in[11]; ba.wu[1]=wu1p; ba.bu[1]=(const float*)d_in[15]; ba.outb[1]=w1p_b;
  ba.bd[2]=(const float*)d_in[19]; ba.bs[2]=(const float*)d_in[17]; ba.wu[2]=wu2a; ba.bu[2]=(const float*)d_in[21]; ba.outb[2]=w2a_b;
  ba.bd[3]=(const float*)d_in[25]; ba.bs[3]=(const float*)d_in[23]; ba.wu[3]=wu2p; ba.bu[3]=(const float*)d_in[27]; ba.outb[3]=w2p_b;
  k_biasfold<<<4, 128, 0, stream>>>(ba);

  const int GEMM_GRID = (NN + 127)/128;   // 782
  const int* off_pa = off2;        const int* deg_pa = deg2;
  const int* off_ap = off2 + NN;   const int* deg_ap = deg2 + NN;

  auto bn_block = [&](float* h, const float* g, const float* be){
    hipMemsetAsync(stats, 0, 256*4, stream);
    k_stats <<<256, 256, 0, stream>>>(h, stats, NN);
    k_bnprep<<<1, 128, 0, stream>>>(stats, g, be, bnsc, NN);
    k_bn    <<<NN*32/256, 256, 0, stream>>>(h, bnsc, NN);
  };

  // ---- layer 1, author (p2a) ----
  k_gemm_mfma<<<GEMM_GRID, 256, 0, stream>>>(x_paper, 128, Wf[1], 4, 0, nullptr, nullptr, nullptr, B3, NN);
  k_agg <<<NN/2, 256, 0, stream>>>(B3, off_pa, deg_pa, col_pa, B4);
  k_gemm_mfma<<<GEMM_GRID, 256, 0, stream>>>(x_author, 256, Wf[0], 8, 0, nullptr, nullptr, nullptr, B1, NN);
  k_gemm_mfma<<<GEMM_GRID, 256, 0, stream>>>(x_author, 256, Wf[0], 8, 4, w1a_b, B1, B4, B1, NN);
  bn_block(B1, (const float*)d_in[28], (const float*)d_in[29]);

  // ---- layer 1, paper (a2p) ----
  k_gemm_mfma<<<GEMM_GRID, 256, 0, stream>>>(x_author, 256, Wf[3], 8, 0, nullptr, nullptr, nullptr, B3, NN);
  k_gemm_mfma<<<GEMM_GRID, 256, 0, stream>>>(x_author, 256, Wf[3], 8, 4, nullptr, B3, nullptr, B3, NN);
  k_agg <<<NN/2, 256, 0, stream>>>(B3, off_ap, deg_ap, col_ap, B4);
  k_gemm_mfma<<<GEMM_GRID, 256, 0, stream>>>(x_paper, 128, Wf[2], 4, 0, w1p_b, B4, nullptr, B2, NN);
  bn_block(B2, (const float*)d_in[30], (const float*)d_in[31]);

  // ---- layer 2, author (p2a; src = B2, dst = B1) ----
  k_gemm_mfma<<<GEMM_GRID, 256, 0, stream>>>(B2, 128, Wf[5], 4, 0, nullptr, nullptr, nullptr, B3, NN);
  k_agg <<<NN/2, 256, 0, stream>>>(B3, off_pa, deg_pa, col_pa, B4);
  k_gemm_mfma<<<GEMM_GRID, 256, 0, stream>>>(B1, 128, Wf[4], 4, 0, w2a_b, B4, nullptr, B3, NN);  // h_a2 -> B3
  bn_block(B3, (const float*)d_in[32], (const float*)d_in[33]);
  k_head<4><<<(NN + 255)/256, 256, 0, stream>>>(B3, (const float*)d_in[36], (const float*)d_in[37],
                                                (float*)d_out, NN);

  // ---- layer 2, paper (a2p; src = B1, dst = B2) ----
  k_gemm_mfma<<<GEMM_GRID, 256, 0, stream>>>(B1, 128, Wf[7], 4, 0, nullptr, nullptr, nullptr, B4, NN);
  k_agg <<<NN/2, 256, 0, stream>>>(B4, off_ap, deg_ap, col_ap, B1);          // agg -> B1 (free)
  k_gemm_mfma<<<GEMM_GRID, 256, 0, stream>>>(B2, 128, Wf[6], 4, 0, w2p_b, B1, nullptr, B4, NN);  // h_p2 -> B4
  bn_block(B4, (const float*)d_in[34], (const float*)d_in[35]);
  k_head<7><<<(NN + 255)/256, 256, 0, stream>>>(B4, (const float*)d_in[38], (const float*)d_in[39],
                                                (float*)d_out + (size_t)NN*4, NN);
}

// Round 4
// 1495.810 us; speedup vs baseline: 1.2042x; 1.1659x over previous
//
#include <hip/hip_runtime.h>

#define NN 100000      // nodes per type (authors == papers == 100000)
#define NE 500000      // edges per relation
#define HD 128         // hidden
#define NBLK 391       // ceil(NN/256)

typedef float f32x4v __attribute__((ext_vector_type(4)));
typedef short s16x8  __attribute__((ext_vector_type(8)));

// float -> bf16 bits, RNE
static __device__ __forceinline__ unsigned f2bf_bits(float f){
  unsigned u = __float_as_uint(f);
  return (u + 0x7FFF + ((u >> 16) & 1)) >> 16;
}

static __device__ __forceinline__ void split8(const float* a, s16x8& hi, s16x8& lo){
  #pragma unroll
  for (int j = 0; j < 8; ++j){
    float f = a[j];
    unsigned hb = f2bf_bits(f);
    float hf = __uint_as_float(hb << 16);
    float lf = f - hf;
    hi[j] = (short)hb;
    lo[j] = (short)f2bf_bits(lf);
  }
}

// ============================ CSR build =================================
__global__ void k_count(const int* __restrict__ ei_pa, const int* __restrict__ ei_ap,
                        int* __restrict__ deg2){
  int idx = blockIdx.x * 256 + threadIdx.x;
  if (idx < NE)        atomicAdd(&deg2[      ei_pa[NE + idx]], 1);
  else if (idx < 2*NE) atomicAdd(&deg2[NN + ei_ap[NE + (idx - NE)]], 1);
}

__global__ void k_bsum(const int* __restrict__ deg2, int* __restrict__ bsum){
  int rel = blockIdx.x / NBLK, b = blockIdx.x % NBLK;
  int i = b*256 + threadIdx.x;
  int v = (i < NN) ? deg2[rel*NN + i] : 0;
  __shared__ int s[256];
  s[threadIdx.x] = v; __syncthreads();
  for (int o = 128; o > 0; o >>= 1){
    if (threadIdx.x < o) s[threadIdx.x] += s[threadIdx.x + o];
    __syncthreads();
  }
  if (threadIdx.x == 0) bsum[rel*512 + b] = s[0];
}

__global__ void k_bscan(const int* __restrict__ bsum, int* __restrict__ bsoff){
  int rel = blockIdx.x, t = threadIdx.x;
  int v = (t < NBLK) ? bsum[rel*512 + t] : 0;
  __shared__ int s[512];
  s[t] = v; __syncthreads();
  for (int o = 1; o < 512; o <<= 1){
    int x = (t >= o) ? s[t - o] : 0;
    __syncthreads();
    s[t] += x;
    __syncthreads();
  }
  bsoff[rel*512 + t] = s[t] - v;   // exclusive
}

__global__ void k_scanC(const int* __restrict__ deg2, const int* __restrict__ bsoff,
                        int* __restrict__ off2, int* __restrict__ cur2){
  int rel = blockIdx.x / NBLK, b = blockIdx.x % NBLK;
  int i = b*256 + threadIdx.x, t = threadIdx.x;
  int v = (i < NN) ? deg2[rel*NN + i] : 0;
  __shared__ int s[256];
  s[t] = v; __syncthreads();
  for (int o = 1; o < 256; o <<= 1){
    int x = (t >= o) ? s[t - o] : 0;
    __syncthreads();
    s[t] += x;
    __syncthreads();
  }
  if (i < NN){
    int o = bsoff[rel*512 + b] + s[t] - v;
    off2[rel*NN + i] = o;
    cur2[rel*NN + i] = o;
  }
}

__global__ void k_fill(const int* __restrict__ ei_pa, const int* __restrict__ ei_ap,
                       int* __restrict__ cur2,
                       int* __restrict__ col_pa, int* __restrict__ col_ap){
  int idx = blockIdx.x * 256 + threadIdx.x;
  if (idx < NE){
    int s = ei_pa[idx], d = ei_pa[NE + idx];
    int pos = atomicAdd(&cur2[d], 1);
    col_pa[pos] = s;
  } else if (idx < 2*NE){
    int e = idx - NE;
    int s = ei_ap[e], d = ei_ap[NE + e];
    int pos = atomicAdd(&cur2[NN + d], 1);
    col_ap[pos] = s;
  }
}

// ============================ weight folding ============================
// W'[k][n] = (wd @ wu_half)[k][n], written in MFMA B-FRAGMENT ORDER, bf16
// hi/lo: frag pair (nt, kc) occupies 1024 shorts (hi 0..511, lo 512..1023);
// within a half, lane*8 + j where lane = quad*16 + (n&15), k = kc*32+quad*8+j.
struct FoldDesc { const float* A; const float* B; short* Cf; };
struct FoldArgs { FoldDesc d[8]; int rs[9]; };

__global__ void k_fold(FoldArgs fa){
  int row = blockIdx.x;
  int seg = 0;
  #pragma unroll
  for (int s = 0; s < 8; ++s) if (row >= fa.rs[s+1]) seg = s + 1;
  int m = row - fa.rs[seg];             // k index of W'
  int KC = (fa.rs[seg+1] - fa.rs[seg]) >> 5;
  const float* A = fa.d[seg].A + (size_t)m * 128;
  const float* B = fa.d[seg].B;
  int n = threadIdx.x;
  float acc = 0.f;
  for (int k = 0; k < 128; ++k) acc += A[k] * B[k*128 + n];
  unsigned hb = f2bf_bits(acc);
  float hf = __uint_as_float(hb << 16);
  unsigned lb = f2bf_bits(acc - hf);
  int kc = m >> 5, quad = (m >> 3) & 3, j = m & 7;
  int lane = quad*16 + (n & 15), nt = n >> 4;
  size_t fb = (size_t)(nt*KC + kc) * 1024 + lane*8 + j;
  fa.d[seg].Cf[fb]       = (short)hb;
  fa.d[seg].Cf[fb + 512] = (short)lb;
}

// b' = bd@wu_top + bs@wu_bot + bu
struct BiasArgs { const float* bd[4]; const float* bs[4]; const float* wu[4];
                  const float* bu[4]; float* outb[4]; };
__global__ void k_biasfold(BiasArgs ba){
  int s = blockIdx.x, j = threadIdx.x;
  const float* wu = ba.wu[s];
  float acc = ba.bu[s][j];
  for (int k = 0; k < 128; ++k)
    acc += ba.bd[s][k] * wu[k*128 + j] + ba.bs[s][k] * wu[(128 + k)*128 + j];
  ba.outb[s][j] = acc;
}

// ============================ MFMA GEMM =================================
// C[M,128] = A[:, kc0*32 : +128] @ W' (+bias)(+extra)(+extra2)
// B table (64 KB, 4 kc x 8 nt x hi/lo x 1KB) staged to LDS once per block;
// K-loop reads B via ds_read_b128 (conflict-free) and streams A from global
// with register double-buffering. Epilogue transposes C through LDS (reusing
// the B buffer) so global stores are full 512B-contiguous segments (no RFO).
__global__ __launch_bounds__(256)
void k_gemm_mfma(const float* __restrict__ A, int lda,
                 const short* __restrict__ Bf, int KCtot, int kc0,
                 const float* __restrict__ bias, const float* __restrict__ extra,
                 const float* __restrict__ extra2, float* __restrict__ C, int M)
{
  __shared__ __align__(16) char smem[65536];
  short* Bs = (short*)smem;

  const int tid  = threadIdx.x;
  const int wave = tid >> 6, lane = tid & 63;
  const int li   = lane & 15, quad = lane >> 4;
  const int rowT = blockIdx.x * 128 + wave * 32;

  // ---- stage B table (64 KB) into LDS: 16 coalesced 16B loads/thread ----
  #pragma unroll
  for (int c = 0; c < 16; ++c){
    int id   = c*256 + tid;          // chunk of 8 shorts, 0..4095
    int fidx = id >> 6, l = id & 63; // fidx = (kc*8+nt)*2+h
    int kc = fidx >> 4, nt = (fidx >> 1) & 7, h = fidx & 1;
    const short* gp = Bf + (size_t)(nt*KCtot + kc0 + kc)*1024 + h*512 + l*8;
    *(s16x8*)(Bs + fidx*512 + l*8) = *(const s16x8*)gp;
  }

  // ---- A register double-buffer ----
  float4 c0[2], c1[2], n0[2], n1[2];
  auto loadA = [&](int kc, float4* p0, float4* p1){
    #pragma unroll
    for (int mt = 0; mt < 2; ++mt){
      int row = rowT + mt*16 + li;
      if (row < M){
        const float* ap = A + (size_t)row*lda + (kc0 + kc)*32 + quad*8;
        p0[mt] = *(const float4*)ap;
        p1[mt] = *(const float4*)(ap + 4);
      } else {
        p0[mt] = make_float4(0.f,0.f,0.f,0.f);
        p1[mt] = make_float4(0.f,0.f,0.f,0.f);
      }
    }
  };
  loadA(0, c0, c1);

  __syncthreads();

  f32x4v acc[2][8];
  #pragma unroll
  for (int mt = 0; mt < 2; ++mt)
    #pragma unroll
    for (int nt = 0; nt < 8; ++nt)
      acc[mt][nt] = (f32x4v){0.f, 0.f, 0.f, 0.f};

  #pragma unroll
  for (int kc = 0; kc < 4; ++kc){
    if (kc < 3) loadA(kc+1, n0, n1);
    s16x8 ah[2], al[2];
    #pragma unroll
    for (int mt = 0; mt < 2; ++mt){
      float av[8] = {c0[mt].x, c0[mt].y, c0[mt].z, c0[mt].w,
                     c1[mt].x, c1[mt].y, c1[mt].z, c1[mt].w};
      split8(av, ah[mt], al[mt]);
    }
    #pragma unroll
    for (int nt = 0; nt < 8; ++nt){
      const short* bp = Bs + ((kc*8 + nt) << 10) + lane*8;
      s16x8 bh = *(const s16x8*)bp;
      s16x8 bl = *(const s16x8*)(bp + 512);
      #pragma unroll
      for (int mt = 0; mt < 2; ++mt){
        acc[mt][nt] = __builtin_amdgcn_mfma_f32_16x16x32_bf16(ah[mt], bh, acc[mt][nt], 0, 0, 0);
        acc[mt][nt] = __builtin_amdgcn_mfma_f32_16x16x32_bf16(al[mt], bh, acc[mt][nt], 0, 0, 0);
        acc[mt][nt] = __builtin_amdgcn_mfma_f32_16x16x32_bf16(ah[mt], bl, acc[mt][nt], 0, 0, 0);
      }
    }
    #pragma unroll
    for (int mt = 0; mt < 2; ++mt){ c0[mt] = n0[mt]; c1[mt] = n1[mt]; }
  }

  // ---- epilogue: transpose through LDS for fully-coalesced stores ----
  __syncthreads();                 // everyone done reading B frags
  float* Cs = (float*)smem;        // 128 x 128 fp32 tile (64 KB)
  #pragma unroll
  for (int mt = 0; mt < 2; ++mt)
    #pragma unroll
    for (int r = 0; r < 4; ++r){
      int lrow = wave*32 + mt*16 + quad*4 + r;
      #pragma unroll
      for (int nt = 0; nt < 8; ++nt)
        Cs[lrow*128 + nt*16 + li] = acc[mt][nt][r];
    }
  // intra-wave dependence only (wave reads back its own 32 rows)
  int col4 = lane & 31;            // float4 column index
  float4 bias4 = make_float4(0.f,0.f,0.f,0.f);
  if (bias) bias4 = ((const float4*)bias)[col4];
  #pragma unroll
  for (int i = 0; i < 16; ++i){
    int row  = wave*32 + i*2 + (lane >> 5);
    int grow = blockIdx.x*128 + row;
    if (grow >= M) continue;
    float4 v = ((const float4*)(Cs + row*128))[col4];
    v.x += bias4.x; v.y += bias4.y; v.z += bias4.z; v.w += bias4.w;
    if (extra){
      float4 e = ((const float4*)(extra + (size_t)grow*128))[col4];
      v.x += e.x; v.y += e.y; v.z += e.z; v.w += e.w;
    }
    if (extra2){
      float4 e = ((const float4*)(extra2 + (size_t)grow*128))[col4];
      v.x += e.x; v.y += e.y; v.z += e.z; v.w += e.w;
    }
    ((float4*)(C + (size_t)grow*128))[col4] = v;
  }
}

// ============================ mean-aggregate ============================
__global__ void k_agg(const float* __restrict__ t, const int* __restrict__ off,
                      const int* __restrict__ deg, const int* __restrict__ col,
                      float* __restrict__ o){
  int d = blockIdx.x * 2 + (threadIdx.x >> 7);
  int c = threadIdx.x & 127;
  int s0 = off[d], cnt = deg[d];
  float acc = 0.f;
  for (int i = 0; i < cnt; ++i){
    int s = col[s0 + i];
    acc += t[(size_t)s*128 + c];
  }
  float inv = 1.0f / (float)(cnt > 0 ? cnt : 1);
  o[(size_t)d*128 + c] = acc * inv;
}

// ============================ batchnorm + lrelu =========================
__global__ void k_stats(const float* __restrict__ x, float* __restrict__ stats, int M){
  int c = threadIdx.x & 127, half = threadIdx.x >> 7;
  float s = 0.f, s2 = 0.f;
  for (int r = blockIdx.x*2 + half; r < M; r += gridDim.x*2){
    float v = x[(size_t)r*128 + c];
    s += v; s2 += v*v;
  }
  __shared__ float sh[256];
  sh[threadIdx.x] = s; __syncthreads();
  if (half == 0) atomicAdd(&stats[c], s + sh[threadIdx.x + 128]);
  __syncthreads();
  sh[threadIdx.x] = s2; __syncthreads();
  if (half == 0) atomicAdd(&stats[128 + c], s2 + sh[threadIdx.x + 128]);
}

__global__ void k_bnprep(const float* __restrict__ stats, const float* __restrict__ g,
                         const float* __restrict__ b, float* __restrict__ sc, int M){
  int c = threadIdx.x;
  float invN = 1.0f / (float)M;
  float m  = stats[c] * invN;
  float var = stats[128 + c] * invN - m*m;
  float scale = g[c] / sqrtf(var + 1.0f);
  sc[c] = scale;
  sc[128 + c] = b[c] - m*scale;
}

__global__ void k_bn(float* __restrict__ x, const float* __restrict__ sc, int M){
  int idx = blockIdx.x*256 + threadIdx.x;   // float4 index
  if (idx >= M*32) return;
  int c = (idx & 31) * 4;
  float4 v = ((float4*)x)[idx];
  float s0=sc[c],s1=sc[c+1],s2=sc[c+2],s3=sc[c+3];
  float h0=sc[128+c],h1=sc[129+c],h2=sc[130+c],h3=sc[131+c];
  v.x = v.x*s0 + h0; v.x = v.x >= 0.f ? v.x : 0.01f*v.x;
  v.y = v.y*s1 + h1; v.y = v.y >= 0.f ? v.y : 0.01f*v.y;
  v.z = v.z*s2 + h2; v.z = v.z >= 0.f ? v.z : 0.01f*v.z;
  v.w = v.w*s3 + h3; v.w = v.w >= 0.f ? v.w : 0.01f*v.w;
  ((float4*)x)[idx] = v;
}

// ============================ heads =====================================
template<int LC>
__global__ void k_head(const float* __restrict__ h, const float* __restrict__ w,
                       const float* __restrict__ b, float* __restrict__ o, int M){
  __shared__ float ws[128*LC];
  __shared__ float bs[LC];
  for (int i = threadIdx.x; i < 128*LC; i += 256) ws[i] = w[i];
  if (threadIdx.x < LC) bs[threadIdx.x] = b[threadIdx.x];
  __syncthreads();
  int r = blockIdx.x*256 + threadIdx.x;
  if (r >= M) return;
  float acc[LC];
  #pragma unroll
  for (int c = 0; c < LC; ++c) acc[c] = bs[c];
  const float4* hr = (const float4*)(h + (size_t)r*128);
  for (int k4 = 0; k4 < 32; ++k4){
    float4 v = hr[k4];
    int k = k4*4;
    #pragma unroll
    for (int c = 0; c < LC; ++c)
      acc[c] += v.x*ws[k*LC+c] + v.y*ws[(k+1)*LC+c] + v.z*ws[(k+2)*LC+c] + v.w*ws[(k+3)*LC+c];
  }
  #pragma unroll
  for (int c = 0; c < LC; ++c) o[(size_t)r*LC + c] = acc[c];
}

// ============================ launch ====================================
extern "C" void kernel_launch(void* const* d_in, const int* in_sizes, int n_in,
                              void* d_out, int out_size, void* d_ws, size_t ws_size,
                              hipStream_t stream) {
  const float* x_author = (const float*)d_in[0];   // [NN,256]
  const float* x_paper  = (const float*)d_in[1];   // [NN,128]
  const int*   ei_pa    = (const int*)d_in[2];     // [2,NE]
  const int*   ei_ap    = (const int*)d_in[3];     // [2,NE]

  char* p = (char*)d_ws;
  auto alloc = [&](size_t bytes) -> void* {
    void* r = (void*)p; p += (bytes + 255) & ~(size_t)255; return r;
  };
  // folded weights in fragment order:
  // seg0 w1a_d(K=256) seg1 w1a_s(128) seg2 w1p_d(128) seg3 w1p_s(256)
  // seg4 w2a_d(128) seg5 w2a_s(128) seg6 w2p_d(128) seg7 w2p_s(128)
  int rows[8] = {256,128,128,256,128,128,128,128};
  short* Wf[8];
  for (int i = 0; i < 8; ++i) Wf[i] = (short*)alloc((size_t)rows[i]*128*2*2);
  float* w1a_b = (float*)alloc(128*4);      float* w1p_b = (float*)alloc(128*4);
  float* w2a_b = (float*)alloc(128*4);      float* w2p_b = (float*)alloc(128*4);
  float* stats = (float*)alloc(256*4);      float* bnsc  = (float*)alloc(256*4);
  int* deg2  = (int*)alloc(2*NN*4);
  int* off2  = (int*)alloc(2*NN*4);
  int* cur2  = (int*)alloc(2*NN*4);
  int* col_pa = (int*)alloc(NE*4);
  int* col_ap = (int*)alloc(NE*4);
  int* bsum  = (int*)alloc(1024*4);
  int* bsoff = (int*)alloc(1024*4);
  const size_t NB = (size_t)NN * 128;
  float* B1 = (float*)alloc(NB*4);  // h_author (layer1, activated)
  float* B2 = (float*)alloc(NB*4);  // h_paper
  float* B3 = (float*)alloc(NB*4);  // temp src-transform / h_a2
  float* B4 = (float*)alloc(NB*4);  // agg / temp / h_p2

  // ---- CSR build (shared by both layers) ----
  hipMemsetAsync(deg2, 0, 2*NN*4, stream);
  k_count<<<(2*NE + 255)/256, 256, 0, stream>>>(ei_pa, ei_ap, deg2);
  k_bsum <<<2*NBLK, 256, 0, stream>>>(deg2, bsum);
  k_bscan<<<2, 512, 0, stream>>>(bsum, bsoff);
  k_scanC<<<2*NBLK, 256, 0, stream>>>(deg2, bsoff, off2, cur2);
  k_fill <<<(2*NE + 255)/256, 256, 0, stream>>>(ei_pa, ei_ap, cur2, col_pa, col_ap);

  // ---- fold weights ----
  FoldArgs fa;
  const float* wu1a = (const float*)d_in[8];
  const float* wu1p = (const float*)d_in[14];
  const float* wu2a = (const float*)d_in[20];
  const float* wu2p = (const float*)d_in[26];
  fa.d[0] = { (const float*)d_in[6],  wu1a,           Wf[0] };  // wd(256)@wu_top
  fa.d[1] = { (const float*)d_in[4],  wu1a + 128*128, Wf[1] };  // ws(128)@wu_bot
  fa.d[2] = { (const float*)d_in[12], wu1p,           Wf[2] };
  fa.d[3] = { (const float*)d_in[10], wu1p + 128*128, Wf[3] };
  fa.d[4] = { (const float*)d_in[18], wu2a,           Wf[4] };
  fa.d[5] = { (const float*)d_in[16], wu2a + 128*128, Wf[5] };
  fa.d[6] = { (const float*)d_in[24], wu2p,           Wf[6] };
  fa.d[7] = { (const float*)d_in[22], wu2p + 128*128, Wf[7] };
  fa.rs[0] = 0;
  for (int i = 0; i < 8; ++i) fa.rs[i+1] = fa.rs[i] + rows[i];
  k_fold<<<fa.rs[8], 128, 0, stream>>>(fa);

  BiasArgs ba;
  ba.bd[0]=(const float*)d_in[7];  ba.bs[0]=(const float*)d_in[5];  ba.wu[0]=wu1a; ba.bu[0]=(const float*)d_in[9];  ba.outb[0]=w1a_b;
  ba.bd[1]=(const float*)d_in[13]; ba.bs[1]=(const float*)d_in[11]; ba.wu[1]=wu1p; ba.bu[1]=(const float*)d_in[15]; ba.outb[1]=w1p_b;
  ba.bd[2]=(const float*)d_in[19]; ba.bs[2]=(const float*)d_in[17]; ba.wu[2]=wu2a; ba.bu[2]=(const float*)d_in[21]; ba.outb[2]=w2a_b;
  ba.bd[3]=(const float*)d_in[25]; ba.bs[3]=(const float*)d_in[23]; ba.wu[3]=wu2p; ba.bu[3]=(const float*)d_in[27]; ba.outb[3]=w2p_b;
  k_biasfold<<<4, 128, 0, stream>>>(ba);

  const int GEMM_GRID = (NN + 127)/128;   // 782
  const int* off_pa = off2;        const int* deg_pa = deg2;
  const int* off_ap = off2 + NN;   const int* deg_ap = deg2 + NN;

  auto bn_block = [&](float* h, const float* g, const float* be){
    hipMemsetAsync(stats, 0, 256*4, stream);
    k_stats <<<256, 256, 0, stream>>>(h, stats, NN);
    k_bnprep<<<1, 128, 0, stream>>>(stats, g, be, bnsc, NN);
    k_bn    <<<NN*32/256, 256, 0, stream>>>(h, bnsc, NN);
  };

  // ---- layer 1, author (p2a) ----
  k_gemm_mfma<<<GEMM_GRID, 256, 0, stream>>>(x_paper, 128, Wf[1], 4, 0, nullptr, nullptr, nullptr, B3, NN);
  k_agg <<<NN/2, 256, 0, stream>>>(B3, off_pa, deg_pa, col_pa, B4);
  k_gemm_mfma<<<GEMM_GRID, 256, 0, stream>>>(x_author, 256, Wf[0], 8, 0, nullptr, nullptr, nullptr, B1, NN);
  k_gemm_mfma<<<GEMM_GRID, 256, 0, stream>>>(x_author, 256, Wf[0], 8, 4, w1a_b, B1, B4, B1, NN);
  bn_block(B1, (const float*)d_in[28], (const float*)d_in[29]);

  // ---- layer 1, paper (a2p) ----
  k_gemm_mfma<<<GEMM_GRID, 256, 0, stream>>>(x_author, 256, Wf[3], 8, 0, nullptr, nullptr, nullptr, B3, NN);
  k_gemm_mfma<<<GEMM_GRID, 256, 0, stream>>>(x_author, 256, Wf[3], 8, 4, nullptr, B3, nullptr, B3, NN);
  k_agg <<<NN/2, 256, 0, stream>>>(B3, off_ap, deg_ap, col_ap, B4);
  k_gemm_mfma<<<GEMM_GRID, 256, 0, stream>>>(x_paper, 128, Wf[2], 4, 0, w1p_b, B4, nullptr, B2, NN);
  bn_block(B2, (const float*)d_in[30], (const float*)d_in[31]);

  // ---- layer 2, author (p2a; src = B2, dst = B1) ----
  k_gemm_mfma<<<GEMM_GRID, 256, 0, stream>>>(B2, 128, Wf[5], 4, 0, nullptr, nullptr, nullptr, B3, NN);
  k_agg <<<NN/2, 256, 0, stream>>>(B3, off_pa, deg_pa, col_pa, B4);
  k_gemm_mfma<<<GEMM_GRID, 256, 0, stream>>>(B1, 128, Wf[4], 4, 0, w2a_b, B4, nullptr, B3, NN);  // h_a2 -> B3
  bn_block(B3, (const float*)d_in[32], (const float*)d_in[33]);
  k_head<4><<<(NN + 255)/256, 256, 0, stream>>>(B3, (const float*)d_in[36], (const float*)d_in[37],
                                                (float*)d_out, NN);

  // ---- layer 2, paper (a2p; src = B1, dst = B2) ----
  k_gemm_mfma<<<GEMM_GRID, 256, 0, stream>>>(B1, 128, Wf[7], 4, 0, nullptr, nullptr, nullptr, B4, NN);
  k_agg <<<NN/2, 256, 0, stream>>>(B4, off_ap, deg_ap, col_ap, B1);          // agg -> B1 (free)
  k_gemm_mfma<<<GEMM_GRID, 256, 0, stream>>>(B2, 128, Wf[6], 4, 0, w2p_b, B1, nullptr, B4, NN);  // h_p2 -> B4
  bn_block(B4, (const float*)d_in[34], (const float*)d_in[35]);
  k_head<7><<<(NN + 255)/256, 256, 0, stream>>>(B4, (const float*)d_in[38], (const float*)d_in[39],
                                                (float*)d_out + (size_t)NN*4, NN);
}

// Round 5
// 874.439 us; speedup vs baseline: 2.0599x; 1.7106x over previous
//
#include <hip/hip_runtime.h>

#define NN 100000      // nodes per type (authors == papers == 100000)
#define NE 500000      // edges per relation
#define HD 128         // hidden
#define NBLK 391       // ceil(NN/256)

typedef float f32x4v __attribute__((ext_vector_type(4)));
typedef short s16x8  __attribute__((ext_vector_type(8)));

// float -> bf16 bits, RNE
static __device__ __forceinline__ unsigned f2bf_bits(float f){
  unsigned u = __float_as_uint(f);
  return (u + 0x7FFF + ((u >> 16) & 1)) >> 16;
}

static __device__ __forceinline__ void split8(const float* a, s16x8& hi, s16x8& lo){
  #pragma unroll
  for (int j = 0; j < 8; ++j){
    float f = a[j];
    unsigned hb = f2bf_bits(f);
    float hf = __uint_as_float(hb << 16);
    float lf = f - hf;
    hi[j] = (short)hb;
    lo[j] = (short)f2bf_bits(lf);
  }
}

// ============================ CSR build =================================
__global__ void k_count(const int* __restrict__ ei_pa, const int* __restrict__ ei_ap,
                        int* __restrict__ deg2){
  int idx = blockIdx.x * 256 + threadIdx.x;
  if (idx < NE)        atomicAdd(&deg2[      ei_pa[NE + idx]], 1);
  else if (idx < 2*NE) atomicAdd(&deg2[NN + ei_ap[NE + (idx - NE)]], 1);
}

__global__ void k_bsum(const int* __restrict__ deg2, int* __restrict__ bsum){
  int rel = blockIdx.x / NBLK, b = blockIdx.x % NBLK;
  int i = b*256 + threadIdx.x;
  int v = (i < NN) ? deg2[rel*NN + i] : 0;
  __shared__ int s[256];
  s[threadIdx.x] = v; __syncthreads();
  for (int o = 128; o > 0; o >>= 1){
    if (threadIdx.x < o) s[threadIdx.x] += s[threadIdx.x + o];
    __syncthreads();
  }
  if (threadIdx.x == 0) bsum[rel*512 + b] = s[0];
}

__global__ void k_bscan(const int* __restrict__ bsum, int* __restrict__ bsoff){
  int rel = blockIdx.x, t = threadIdx.x;
  int v = (t < NBLK) ? bsum[rel*512 + t] : 0;
  __shared__ int s[512];
  s[t] = v; __syncthreads();
  for (int o = 1; o < 512; o <<= 1){
    int x = (t >= o) ? s[t - o] : 0;
    __syncthreads();
    s[t] += x;
    __syncthreads();
  }
  bsoff[rel*512 + t] = s[t] - v;   // exclusive
}

__global__ void k_scanC(const int* __restrict__ deg2, const int* __restrict__ bsoff,
                        int* __restrict__ off2, int* __restrict__ cur2){
  int rel = blockIdx.x / NBLK, b = blockIdx.x % NBLK;
  int i = b*256 + threadIdx.x, t = threadIdx.x;
  int v = (i < NN) ? deg2[rel*NN + i] : 0;
  __shared__ int s[256];
  s[t] = v; __syncthreads();
  for (int o = 1; o < 256; o <<= 1){
    int x = (t >= o) ? s[t - o] : 0;
    __syncthreads();
    s[t] += x;
    __syncthreads();
  }
  if (i < NN){
    int o = bsoff[rel*512 + b] + s[t] - v;
    off2[rel*NN + i] = o;
    cur2[rel*NN + i] = o;
  }
}

__global__ void k_fill(const int* __restrict__ ei_pa, const int* __restrict__ ei_ap,
                       int* __restrict__ cur2,
                       int* __restrict__ col_pa, int* __restrict__ col_ap){
  int idx = blockIdx.x * 256 + threadIdx.x;
  if (idx < NE){
    int s = ei_pa[idx], d = ei_pa[NE + idx];
    int pos = atomicAdd(&cur2[d], 1);
    col_pa[pos] = s;
  } else if (idx < 2*NE){
    int e = idx - NE;
    int s = ei_ap[e], d = ei_ap[NE + e];
    int pos = atomicAdd(&cur2[NN + d], 1);
    col_ap[pos] = s;
  }
}

// ============================ weight folding ============================
// W' = A(128-col rows) @ B(wu half). Written as bf16 hi/lo MFMA B-fragments
// into a combined table at k-chunk offset `off`. Fragment layout (kc-major):
// elem index = ((gkc*8 + nt)*2 + h)*512 + lane*8 + j,
// lane = quad*16 + (n&15), k = gkc*32 + quad*8 + j.
struct FoldDesc { const float* A; const float* B; short* T; int off; };
struct FoldArgs { FoldDesc d[8]; int rs[9]; };

__global__ void k_fold(FoldArgs fa){
  int row = blockIdx.x;
  int seg = 0;
  #pragma unroll
  for (int s = 0; s < 8; ++s) if (row >= fa.rs[s+1]) seg = s + 1;
  int m = row - fa.rs[seg];             // local k index of W'
  const float* A = fa.d[seg].A + (size_t)m * 128;
  const float* B = fa.d[seg].B;
  int n = threadIdx.x;
  float acc = 0.f;
  for (int k = 0; k < 128; ++k) acc += A[k] * B[k*128 + n];
  unsigned hb = f2bf_bits(acc);
  float hf = __uint_as_float(hb << 16);
  unsigned lb = f2bf_bits(acc - hf);
  int gkc = fa.d[seg].off + (m >> 5), quad = (m >> 3) & 3, j = m & 7;
  int lane = quad*16 + (n & 15), nt = n >> 4;
  size_t fb = (size_t)((gkc*8 + nt)*2)*512 + lane*8 + j;
  fa.d[seg].T[fb]       = (short)hb;
  fa.d[seg].T[fb + 512] = (short)lb;
}

// b' = bd@wu_top + bs@wu_bot + bu
struct BiasArgs { const float* bd[4]; const float* bs[4]; const float* wu[4];
                  const float* bu[4]; float* outb[4]; };
__global__ void k_biasfold(BiasArgs ba){
  int s = blockIdx.x, j = threadIdx.x;
  const float* wu = ba.wu[s];
  float acc = ba.bu[s][j];
  for (int k = 0; k < 128; ++k)
    acc += ba.bd[s][k] * wu[k*128 + j] + ba.bs[s][k] * wu[(128 + k)*128 + j];
  ba.outb[s][j] = acc;
}

// ============================ MFMA GEMM =================================
// C[M,128] = A1[:,0:KC1*32] @ B[0:KC1] + A2[:,0:KC2*32] @ B[KC1:] (+bias)
// (+extra). B staged to LDS in groups of 4 k-chunks (64 KB). A register
// double-buffered. Epilogue transposes C via LDS (coalesced 512B stores);
// optional fused BN column stats (sum/sumsq -> atomicAdd per block).
__global__ __launch_bounds__(256)
void k_gemm2(const float* __restrict__ A1, int lda1, int KC1,
             const float* __restrict__ A2, int lda2, int KC2,
             const short* __restrict__ Bf,
             const float* __restrict__ bias, const float* __restrict__ extra,
             float* __restrict__ C, float* __restrict__ stats, int M)
{
  __shared__ __align__(16) char smem[65536];
  short* Bs = (short*)smem;

  const int tid  = threadIdx.x;
  const int wave = tid >> 6, lane = tid & 63;
  const int li   = lane & 15, quad = lane >> 4;
  const int rowT = blockIdx.x * 128 + wave * 32;
  const int KCtot = KC1 + KC2;

  f32x4v acc[2][8];
  #pragma unroll
  for (int mt = 0; mt < 2; ++mt)
    #pragma unroll
    for (int nt = 0; nt < 8; ++nt)
      acc[mt][nt] = (f32x4v){0.f, 0.f, 0.f, 0.f};

  float4 c0[2], c1[2], n0[2], n1[2];
  auto loadA = [&](int gkc, float4* p0, float4* p1){
    const float* Ab; int ld, kk;
    if (gkc < KC1){ Ab = A1; ld = lda1; kk = gkc; }
    else          { Ab = A2; ld = lda2; kk = gkc - KC1; }
    #pragma unroll
    for (int mt = 0; mt < 2; ++mt){
      int row = rowT + mt*16 + li;
      if (row < M){
        const float* ap = Ab + (size_t)row*ld + kk*32 + quad*8;
        p0[mt] = *(const float4*)ap;
        p1[mt] = *(const float4*)(ap + 4);
      } else {
        p0[mt] = make_float4(0.f,0.f,0.f,0.f);
        p1[mt] = make_float4(0.f,0.f,0.f,0.f);
      }
    }
  };
  loadA(0, c0, c1);

  for (int g = 0; g < KCtot; g += 4){
    if (g > 0) __syncthreads();          // prior group's LDS reads done
    const short* src = Bf + (size_t)g*8192;
    #pragma unroll
    for (int c2 = 0; c2 < 16; ++c2){
      int id = c2*256 + tid;
      *(s16x8*)(Bs + id*8) = *(const s16x8*)(src + id*8);
    }
    __syncthreads();
    #pragma unroll
    for (int kc = 0; kc < 4; ++kc){
      int gkc = g + kc;
      if (gkc + 1 < KCtot) loadA(gkc + 1, n0, n1);
      s16x8 ah[2], al[2];
      #pragma unroll
      for (int mt = 0; mt < 2; ++mt){
        float av[8] = {c0[mt].x, c0[mt].y, c0[mt].z, c0[mt].w,
                       c1[mt].x, c1[mt].y, c1[mt].z, c1[mt].w};
        split8(av, ah[mt], al[mt]);
      }
      #pragma unroll
      for (int nt = 0; nt < 8; ++nt){
        const short* bp = Bs + ((kc*8 + nt) << 10) + lane*8;
        s16x8 bh = *(const s16x8*)bp;
        s16x8 bl = *(const s16x8*)(bp + 512);
        #pragma unroll
        for (int mt = 0; mt < 2; ++mt){
          acc[mt][nt] = __builtin_amdgcn_mfma_f32_16x16x32_bf16(ah[mt], bh, acc[mt][nt], 0, 0, 0);
          acc[mt][nt] = __builtin_amdgcn_mfma_f32_16x16x32_bf16(al[mt], bh, acc[mt][nt], 0, 0, 0);
          acc[mt][nt] = __builtin_amdgcn_mfma_f32_16x16x32_bf16(ah[mt], bl, acc[mt][nt], 0, 0, 0);
        }
      }
      #pragma unroll
      for (int mt = 0; mt < 2; ++mt){ c0[mt] = n0[mt]; c1[mt] = n1[mt]; }
    }
  }

  // ---- epilogue: transpose through LDS for coalesced stores ----
  __syncthreads();                 // all LDS B reads done
  float* Cs = (float*)smem;        // 128 x 128 fp32 tile
  #pragma unroll
  for (int mt = 0; mt < 2; ++mt)
    #pragma unroll
    for (int r = 0; r < 4; ++r){
      int lrow = wave*32 + mt*16 + quad*4 + r;
      #pragma unroll
      for (int nt = 0; nt < 8; ++nt)
        Cs[lrow*128 + nt*16 + li] = acc[mt][nt][r];
    }
  // intra-wave only: wave reads back its own 32 rows
  int col4 = lane & 31;
  float4 bias4 = make_float4(0.f,0.f,0.f,0.f);
  if (bias) bias4 = ((const float4*)bias)[col4];
  float4 s1 = make_float4(0.f,0.f,0.f,0.f), s2 = s1;
  #pragma unroll
  for (int i = 0; i < 16; ++i){
    int row  = wave*32 + i*2 + (lane >> 5);
    int grow = blockIdx.x*128 + row;
    if (grow >= M) continue;
    float4 v = ((const float4*)(Cs + row*128))[col4];
    v.x += bias4.x; v.y += bias4.y; v.z += bias4.z; v.w += bias4.w;
    if (extra){
      float4 e = ((const float4*)(extra + (size_t)grow*128))[col4];
      v.x += e.x; v.y += e.y; v.z += e.z; v.w += e.w;
    }
    ((float4*)(C + (size_t)grow*128))[col4] = v;
    s1.x += v.x; s1.y += v.y; s1.z += v.z; s1.w += v.w;
    s2.x += v.x*v.x; s2.y += v.y*v.y; s2.z += v.z*v.z; s2.w += v.w*v.w;
  }
  if (stats){
    __syncthreads();               // done reading Cs; reuse smem for partials
    float* Ss = (float*)smem;      // [256 threads][8]: s1.xyzw, s2.xyzw
    ((float4*)Ss)[tid*2]     = s1;
    ((float4*)Ss)[tid*2 + 1] = s2;
    __syncthreads();
    int c = tid & 127, kind = tid >> 7;     // kind 0 = sum, 1 = sumsq
    int cc4 = c >> 2, comp = c & 3;
    float s = 0.f;
    #pragma unroll
    for (int wv = 0; wv < 4; ++wv)
      #pragma unroll
      for (int hf = 0; hf < 2; ++hf)
        s += Ss[(wv*64 + hf*32 + cc4)*8 + kind*4 + comp];
    atomicAdd(&stats[kind*128 + c], s);
  }
}

// ============================ mean-aggregate ============================
// 8 dst/block, 32 float4-lanes per dst row; 2-edge unroll for MLP.
__global__ __launch_bounds__(256)
void k_agg(const float* __restrict__ t, const int* __restrict__ off,
           const int* __restrict__ deg, const int* __restrict__ col,
           float* __restrict__ o){
  int slot = threadIdx.x >> 5, col4 = threadIdx.x & 31;
  int d = blockIdx.x*8 + slot;
  if (d >= NN) return;
  int s0 = off[d], cnt = deg[d];
  float4 a0 = make_float4(0.f,0.f,0.f,0.f), a1 = a0;
  int i = 0;
  for (; i + 2 <= cnt; i += 2){
    int sa = col[s0 + i], sb = col[s0 + i + 1];
    float4 va = ((const float4*)(t + (size_t)sa*128))[col4];
    float4 vb = ((const float4*)(t + (size_t)sb*128))[col4];
    a0.x += va.x; a0.y += va.y; a0.z += va.z; a0.w += va.w;
    a1.x += vb.x; a1.y += vb.y; a1.z += vb.z; a1.w += vb.w;
  }
  if (i < cnt){
    int sa = col[s0 + i];
    float4 va = ((const float4*)(t + (size_t)sa*128))[col4];
    a0.x += va.x; a0.y += va.y; a0.z += va.z; a0.w += va.w;
  }
  float inv = 1.0f / (float)(cnt > 0 ? cnt : 1);
  float4 r;
  r.x = (a0.x + a1.x)*inv; r.y = (a0.y + a1.y)*inv;
  r.z = (a0.z + a1.z)*inv; r.w = (a0.w + a1.w)*inv;
  ((float4*)(o + (size_t)d*128))[col4] = r;
}

// ============================ batchnorm + lrelu =========================
__global__ void k_bnprep(const float* __restrict__ stats, const float* __restrict__ g,
                         const float* __restrict__ b, float* __restrict__ sc, int M){
  int c = threadIdx.x;
  float invN = 1.0f / (float)M;
  float m  = stats[c] * invN;
  float var = stats[128 + c] * invN - m*m;
  float scale = g[c] / sqrtf(var + 1.0f);
  sc[c] = scale;
  sc[128 + c] = b[c] - m*scale;
}

__global__ void k_bn(float* __restrict__ x, const float* __restrict__ sc, int M){
  int idx = blockIdx.x*256 + threadIdx.x;   // float4 index
  if (idx >= M*32) return;
  int c = (idx & 31) * 4;
  float4 v = ((float4*)x)[idx];
  float s0=sc[c],s1=sc[c+1],s2=sc[c+2],s3=sc[c+3];
  float h0=sc[128+c],h1=sc[129+c],h2=sc[130+c],h3=sc[131+c];
  v.x = v.x*s0 + h0; v.x = v.x >= 0.f ? v.x : 0.01f*v.x;
  v.y = v.y*s1 + h1; v.y = v.y >= 0.f ? v.y : 0.01f*v.y;
  v.z = v.z*s2 + h2; v.z = v.z >= 0.f ? v.z : 0.01f*v.z;
  v.w = v.w*s3 + h3; v.w = v.w >= 0.f ? v.w : 0.01f*v.w;
  ((float4*)x)[idx] = v;
}

// ============================ heads =====================================
template<int LC>
__global__ void k_head(const float* __restrict__ h, const float* __restrict__ w,
                       const float* __restrict__ b, float* __restrict__ o, int M){
  __shared__ float ws[128*LC];
  __shared__ float bs[LC];
  for (int i = threadIdx.x; i < 128*LC; i += 256) ws[i] = w[i];
  if (threadIdx.x < LC) bs[threadIdx.x] = b[threadIdx.x];
  __syncthreads();
  int r = blockIdx.x*256 + threadIdx.x;
  if (r >= M) return;
  float acc[LC];
  #pragma unroll
  for (int c = 0; c < LC; ++c) acc[c] = bs[c];
  const float4* hr = (const float4*)(h + (size_t)r*128);
  for (int k4 = 0; k4 < 32; ++k4){
    float4 v = hr[k4];
    int k = k4*4;
    #pragma unroll
    for (int c = 0; c < LC; ++c)
      acc[c] += v.x*ws[k*LC+c] + v.y*ws[(k+1)*LC+c] + v.z*ws[(k+2)*LC+c] + v.w*ws[(k+3)*LC+c];
  }
  #pragma unroll
  for (int c = 0; c < LC; ++c) o[(size_t)r*LC + c] = acc[c];
}

// ============================ launch ====================================
extern "C" void kernel_launch(void* const* d_in, const int* in_sizes, int n_in,
                              void* d_out, int out_size, void* d_ws, size_t ws_size,
                              hipStream_t stream) {
  const float* x_author = (const float*)d_in[0];   // [NN,256]
  const float* x_paper  = (const float*)d_in[1];   // [NN,128]
  const int*   ei_pa    = (const int*)d_in[2];     // [2,NE]
  const int*   ei_ap    = (const int*)d_in[3];     // [2,NE]

  char* p = (char*)d_ws;
  auto alloc = [&](size_t bytes) -> void* {
    void* r = (void*)p; p += (bytes + 255) & ~(size_t)255; return r;
  };
  // combined fragment tables (bf16 hi/lo, 16 KB per k-chunk):
  short* T_l1a  = (short*)alloc(12u*16384);  // [x_author(8) | agg_pa(4)]
  short* T_l1ps = (short*)alloc( 8u*16384);  // src transform: x_author @ Ws'
  short* T_l1pd = (short*)alloc( 4u*16384);  // dst: x_paper @ Wd'
  short* T_l2a  = (short*)alloc( 8u*16384);  // [h_a(4) | agg(4)]
  short* T_l2p  = (short*)alloc( 8u*16384);
  float* w1a_b = (float*)alloc(128*4);      float* w1p_b = (float*)alloc(128*4);
  float* w2a_b = (float*)alloc(128*4);      float* w2p_b = (float*)alloc(128*4);
  float* stats4 = (float*)alloc(4*256*4);   // 4 BN instances
  float* bnsc  = (float*)alloc(256*4);
  int* deg2  = (int*)alloc(2*NN*4);
  int* off2  = (int*)alloc(2*NN*4);
  int* cur2  = (int*)alloc(2*NN*4);
  int* col_pa = (int*)alloc(NE*4);
  int* col_ap = (int*)alloc(NE*4);
  int* bsum  = (int*)alloc(1024*4);
  int* bsoff = (int*)alloc(1024*4);
  const size_t NB = (size_t)NN * 128;
  float* B1 = (float*)alloc(NB*4);  // h_author L1 / h_p2 out
  float* B2 = (float*)alloc(NB*4);  // h_paper L1
  float* B3 = (float*)alloc(NB*4);  // src transform (l1p) / h_a2
  float* B4 = (float*)alloc(NB*4);  // agg buffer

  // ---- CSR build ----
  hipMemsetAsync(deg2, 0, 2*NN*4, stream);
  hipMemsetAsync(stats4, 0, 4*256*4, stream);
  k_count<<<(2*NE + 255)/256, 256, 0, stream>>>(ei_pa, ei_ap, deg2);
  k_bsum <<<2*NBLK, 256, 0, stream>>>(deg2, bsum);
  k_bscan<<<2, 512, 0, stream>>>(bsum, bsoff);
  k_scanC<<<2*NBLK, 256, 0, stream>>>(deg2, bsoff, off2, cur2);
  k_fill <<<(2*NE + 255)/256, 256, 0, stream>>>(ei_pa, ei_ap, cur2, col_pa, col_ap);

  // ---- fold weights into combined tables ----
  FoldArgs fa;
  const float* wu1a = (const float*)d_in[8];
  const float* wu1p = (const float*)d_in[14];
  const float* wu2a = (const float*)d_in[20];
  const float* wu2p = (const float*)d_in[26];
  // seg: A, wu-half, table, kc-offset, rows
  fa.d[0] = { (const float*)d_in[6],  wu1a,           T_l1a,  0 };  // wd_l1a (256)
  fa.d[1] = { (const float*)d_in[4],  wu1a + 128*128, T_l1a,  8 };  // ws_l1a (128)
  fa.d[2] = { (const float*)d_in[10], wu1p + 128*128, T_l1ps, 0 };  // ws_l1p (256)
  fa.d[3] = { (const float*)d_in[12], wu1p,           T_l1pd, 0 };  // wd_l1p (128)
  fa.d[4] = { (const float*)d_in[18], wu2a,           T_l2a,  0 };  // wd_l2a (128)
  fa.d[5] = { (const float*)d_in[16], wu2a + 128*128, T_l2a,  4 };  // ws_l2a (128)
  fa.d[6] = { (const float*)d_in[24], wu2p,           T_l2p,  0 };  // wd_l2p (128)
  fa.d[7] = { (const float*)d_in[22], wu2p + 128*128, T_l2p,  4 };  // ws_l2p (128)
  int rows[8] = {256,128,256,128,128,128,128,128};
  fa.rs[0] = 0;
  for (int i = 0; i < 8; ++i) fa.rs[i+1] = fa.rs[i] + rows[i];
  k_fold<<<fa.rs[8], 128, 0, stream>>>(fa);

  BiasArgs ba;
  ba.bd[0]=(const float*)d_in[7];  ba.bs[0]=(const float*)d_in[5];  ba.wu[0]=wu1a; ba.bu[0]=(const float*)d_in[9];  ba.outb[0]=w1a_b;
  ba.bd[1]=(const float*)d_in[13]; ba.bs[1]=(const float*)d_in[11]; ba.wu[1]=wu1p; ba.bu[1]=(const float*)d_in[15]; ba.outb[1]=w1p_b;
  ba.bd[2]=(const float*)d_in[19]; ba.bs[2]=(const float*)d_in[17]; ba.wu[2]=wu2a; ba.bu[2]=(const float*)d_in[21]; ba.outb[2]=w2a_b;
  ba.bd[3]=(const float*)d_in[25]; ba.bs[3]=(const float*)d_in[23]; ba.wu[3]=wu2p; ba.bu[3]=(const float*)d_in[27]; ba.outb[3]=w2p_b;
  k_biasfold<<<4, 128, 0, stream>>>(ba);

  const int GG = (NN + 127)/128;   // 782
  const int AGG_GRID = (NN + 7)/8; // 12500
  const int* off_pa = off2;        const int* deg_pa = deg2;
  const int* off_ap = off2 + NN;   const int* deg_ap = deg2 + NN;
  float* st_a1 = stats4;       float* st_p1 = stats4 + 256;
  float* st_a2 = stats4 + 512; float* st_p2 = stats4 + 768;

  // ---- layer 1, author (p2a): agg-first ----
  k_agg<<<AGG_GRID, 256, 0, stream>>>(x_paper, off_pa, deg_pa, col_pa, B4);
  k_gemm2<<<GG, 256, 0, stream>>>(x_author, 256, 8, B4, 128, 4, T_l1a,
                                  w1a_b, nullptr, B1, st_a1, NN);
  k_bnprep<<<1, 128, 0, stream>>>(st_a1, (const float*)d_in[28], (const float*)d_in[29], bnsc, NN);
  k_bn<<<NN*32/256, 256, 0, stream>>>(B1, bnsc, NN);

  // ---- layer 1, paper (a2p): transform-first (src is 256-wide) ----
  k_gemm2<<<GG, 256, 0, stream>>>(x_author, 256, 8, nullptr, 0, 0, T_l1ps,
                                  nullptr, nullptr, B3, nullptr, NN);
  k_agg<<<AGG_GRID, 256, 0, stream>>>(B3, off_ap, deg_ap, col_ap, B4);
  k_gemm2<<<GG, 256, 0, stream>>>(x_paper, 128, 4, nullptr, 0, 0, T_l1pd,
                                  w1p_b, B4, B2, st_p1, NN);
  k_bnprep<<<1, 128, 0, stream>>>(st_p1, (const float*)d_in[30], (const float*)d_in[31], bnsc, NN);
  k_bn<<<NN*32/256, 256, 0, stream>>>(B2, bnsc, NN);

  // ---- layer 2, author (p2a): agg-first on h_paper (B2) ----
  k_agg<<<AGG_GRID, 256, 0, stream>>>(B2, off_pa, deg_pa, col_pa, B4);
  k_gemm2<<<GG, 256, 0, stream>>>(B1, 128, 4, B4, 128, 4, T_l2a,
                                  w2a_b, nullptr, B3, st_a2, NN);
  k_bnprep<<<1, 128, 0, stream>>>(st_a2, (const float*)d_in[32], (const float*)d_in[33], bnsc, NN);
  k_bn<<<NN*32/256, 256, 0, stream>>>(B3, bnsc, NN);
  k_head<4><<<(NN + 255)/256, 256, 0, stream>>>(B3, (const float*)d_in[36], (const float*)d_in[37],
                                                (float*)d_out, NN);

  // ---- layer 2, paper (a2p): agg-first on h_author (B1) ----
  k_agg<<<AGG_GRID, 256, 0, stream>>>(B1, off_ap, deg_ap, col_ap, B4);
  k_gemm2<<<GG, 256, 0, stream>>>(B2, 128, 4, B4, 128, 4, T_l2p,
                                  w2p_b, nullptr, B1, st_p2, NN);
  k_bnprep<<<1, 128, 0, stream>>>(st_p2, (const float*)d_in[34], (const float*)d_in[35], bnsc, NN);
  k_bn<<<NN*32/256, 256, 0, stream>>>(B1, bnsc, NN);
  k_head<7><<<(NN + 255)/256, 256, 0, stream>>>(B1, (const float*)d_in[38], (const float*)d_in[39],
                                                (float*)d_out + (size_t)NN*4, NN);
}